// Round 13
// baseline (396.909 us; speedup 1.0000x reference)
//
#include <hip/hip_runtime.h>
#include <hip/hip_bf16.h>

#define B_ 128
#define L_ 1024
#define T_ 512   // L/2 tokens per parity
#define D_ 768
#define CH_ 96   // D/8 chunks of 8 elems
#define DT_ 513  // output tokens per batch
#define TAU_C 1e-3f   // coarse candidate window (~14 sigma of single-bf16 coarse error)
#define PBUF_ 1024

typedef __attribute__((ext_vector_type(8))) short bf16x8;
typedef __attribute__((ext_vector_type(4))) float f32x4;

typedef const __attribute__((address_space(1))) unsigned int* gas1_t;
typedef __attribute__((address_space(3))) unsigned int* gas3_t;

__device__ __forceinline__ unsigned short f2bf_rne(float x){
    unsigned u = __float_as_uint(x);
    unsigned r = (u + 0x7FFFu + ((u >> 16) & 1u)) >> 16;
    return (unsigned short)r;
}

// ---------------- pack: ALL tokens -> fp64 norm + single bf16, chunk-major per parity ----------------
__global__ __launch_bounds__(256) void pack_k(const float* __restrict__ hs,
                                              unsigned short* __restrict__ Apk,
                                              unsigned short* __restrict__ Bpk,
                                              double* __restrict__ nsq,
                                              int* __restrict__ paircnt){
    __shared__ __align__(16) unsigned short LhS[CH_ * 16 * 8];  // 24.6 KB
    if (blockIdx.x == 0 && threadIdx.x == 0) *paircnt = 0;
    int b = blockIdx.x >> 6, g = blockIdx.x & 63;   // 16 seq tokens per block
    int wv = threadIdx.x >> 6, lane = threadIdx.x & 63;

    #pragma unroll
    for (int rr = 0; rr < 4; ++rr){
        int jj = wv * 4 + rr;                       // 0..15 within block
        long seq = (long)b * L_ + g * 16 + jj;
        const float4* src = (const float4*)(hs + seq * D_);
        float4 f0 = src[lane], f1 = src[lane + 64], f2 = src[lane + 128];
        double s = 0.0;
        s += (double)f0.x*f0.x + (double)f0.y*f0.y + (double)f0.z*f0.z + (double)f0.w*f0.w;
        s += (double)f1.x*f1.x + (double)f1.y*f1.y + (double)f1.z*f1.z + (double)f1.w*f1.w;
        s += (double)f2.x*f2.x + (double)f2.y*f2.y + (double)f2.z*f2.z + (double)f2.w*f2.w;
        #pragma unroll
        for (int off = 32; off; off >>= 1) s += __shfl_xor(s, off);
        if (lane == 0 && (jj & 1)) nsq[seq] = s;    // odd-token norms for refine
        float rn = (float)(1.0 / sqrt(s));
        float4 fv[3] = {f0, f1, f2};
        #pragma unroll
        for (int t = 0; t < 3; ++t){
            int e0 = t * 256 + lane * 4;
            int c = e0 >> 3, ei = e0 & 7;           // ei = 0 or 4
            float vv[4] = {fv[t].x, fv[t].y, fv[t].z, fv[t].w};
            short4 hv;
            #pragma unroll
            for (int e = 0; e < 4; ++e)
                ((short*)&hv)[e] = (short)f2bf_rne(vv[e] * rn);
            int o = c * 128 + ((jj ^ (c & 7)) << 3) + ei;   // XOR-swizzled (shorts)
            *(short4*)(LhS + o) = hv;
        }
    }
    __syncthreads();
    #pragma unroll
    for (int it = 0; it < 6; ++it){
        int linear = it * 256 + threadIdx.x;
        int c = linear >> 4, jj = linear & 15;
        int o = c * 128 + ((jj ^ (c & 7)) << 3);
        int tok = g * 8 + (jj >> 1);
        long go = ((long)(b * CH_ + c) * T_ + tok) * 8;
        if (jj & 1) *(bf16x8*)(Bpk + go) = *(const bf16x8*)(LhS + o);
        else        *(bf16x8*)(Apk + go) = *(const bf16x8*)(LhS + o);
    }
}

// ---------------- coarse: m97-structure 128x128 tile GEMM, 4 waves, 1 buffer, 2 barriers/BK-step,
//                  3 blocks/CU; per-block rowmax + candidate emission vs block max ----------------
// grid: 2048 = xcd(8) x it(4) x jt(4) x bhi(16); wave (wr,wc) = rows wr*64, cols wc*64.
__global__ __launch_bounds__(256, 3) void coarse_k(const unsigned short* __restrict__ Apk,
                                                   const unsigned short* __restrict__ Bpk,
                                                   float* __restrict__ pmax1,
                                                   float* __restrict__ pmax2,
                                                   int*   __restrict__ pj1,
                                                   int* __restrict__ paircnt,
                                                   int2* __restrict__ pairs_ij,
                                                   float* __restrict__ pairv){
    __shared__ __align__(16) char SMEM[32768];     // A[8][128][16B] @0, B @16384

    int bid = blockIdx.x;
    int xcd = bid & 7, rest = bid >> 3;
    int it = rest & 3, jt = (rest >> 2) & 3, bhi = rest >> 4;
    int b = xcd + 8 * bhi;                         // same-b blocks on one XCD

    int tid = threadIdx.x;
    int w = tid >> 6, lane = tid & 63, l15 = lane & 15, l4 = lane >> 4;
    int wr = w >> 1, wc = w & 1;

    long pkbase = (long)b * CH_ * T_;              // units of 8 shorts

    // stage BK-step sk: 16 A segs + 16 B segs (1KB each); wave w does A[w*4+n], B[w*4+n]
    #define STG(sk) do {                                                                   \
        _Pragma("unroll")                                                                  \
        for (int n_ = 0; n_ < 4; ++n_){                                                    \
            int seg_ = w * 4 + n_, c_ = seg_ >> 1, h_ = seg_ & 1;                          \
            const unsigned short* sa_ = Apk + (pkbase + (long)((sk)*8 + c_) * T_ + it * 128 + h_ * 64 + lane) * 8; \
            __builtin_amdgcn_global_load_lds((gas1_t)sa_, (gas3_t)(SMEM + (c_ * 128 + h_ * 64) * 16), 16, 0, 0);   \
            const unsigned short* sb_ = Bpk + (pkbase + (long)((sk)*8 + c_) * T_ + jt * 128 + h_ * 64 + lane) * 8; \
            __builtin_amdgcn_global_load_lds((gas1_t)sb_, (gas3_t)(SMEM + 16384 + (c_ * 128 + h_ * 64) * 16), 16, 0, 0); \
        }                                                                                  \
    } while (0)

    f32x4 acc[4][4];   // row = wr*64 + ib*16 + l4*4+rr, col(block) = wc*64 + jb*16 + l15
    #pragma unroll
    for (int i = 0; i < 4; ++i)
        #pragma unroll
        for (int j = 0; j < 4; ++j) acc[i][j] = (f32x4){0.f, 0.f, 0.f, 0.f};

    STG(0);
    __syncthreads();

    for (int s = 0; s < 12; ++s){
        #pragma unroll
        for (int kk = 0; kk < 2; ++kk){
            bf16x8 ah[4], bh[4];
            #pragma unroll
            for (int ib = 0; ib < 4; ++ib)
                ah[ib] = *(const bf16x8*)(SMEM + (((kk*4 + l4) * 128) + wr * 64 + ib * 16 + l15) * 16);
            #pragma unroll
            for (int jb = 0; jb < 4; ++jb)
                bh[jb] = *(const bf16x8*)(SMEM + 16384 + (((kk*4 + l4) * 128) + wc * 64 + jb * 16 + l15) * 16);
            #pragma unroll
            for (int jb = 0; jb < 4; ++jb)
                #pragma unroll
                for (int ib = 0; ib < 4; ++ib)
                    acc[ib][jb] = __builtin_amdgcn_mfma_f32_16x16x32_bf16(ah[ib], bh[jb], acc[ib][jb], 0, 0, 0);
        }
        __syncthreads();                 // all reads done
        if (s < 11){
            STG(s + 1);
            __syncthreads();             // DMA drained (implicit vmcnt 0) before reads
        }
    }
    #undef STG

    // ---- epilogue overlay ----
    float* pm1s  = (float*)SMEM;                 // [128][2]
    float* pm2s  = (float*)(SMEM + 1024);        // [128][2]
    int*   pjs   = (int*)  (SMEM + 2048);        // [128][2]
    float* m1blk = (float*)(SMEM + 3072);        // [128]
    int2*  pb_ij = (int2*) (SMEM + 4096);        // [1024]
    float* pb_v  = (float*)(SMEM + 12288);       // [1024]
    int*   pcnt_s  = (int*)(SMEM + 16384);
    int*   pbase_s = (int*)(SMEM + 16388);
    if (tid == 0) *pcnt_s = 0;

    // stage 1: per-wave (m1,m2,argmax) over its 64 cols
    #pragma unroll
    for (int ib = 0; ib < 4; ++ib)
        #pragma unroll
        for (int rr = 0; rr < 4; ++rr){
            float m1 = -1e30f, m2 = -1e30f; int j1 = 0;
            #pragma unroll
            for (int jb = 0; jb < 4; ++jb){   // ascending cols: strict > keeps lowest j
                float v = acc[ib][jb][rr];
                int col = wc * 64 + jb * 16 + l15;
                if (v > m1){ m2 = m1; m1 = v; j1 = col; }
                else m2 = fmaxf(m2, v);
            }
            #pragma unroll
            for (int m = 1; m < 16; m <<= 1){
                float o1 = __shfl_xor(m1, m);
                float o2 = __shfl_xor(m2, m);
                int   oj = __shfl_xor(j1, m);
                if (o1 > m1){ m2 = fmaxf(m1, o2); m1 = o1; j1 = oj; }
                else if (o1 < m1){ m2 = fmaxf(m2, o1); }
                else { m2 = m1; j1 = min(j1, oj); }   // exact tie -> gap 0 -> flagged
            }
            if (l15 == 0){
                int row = wr * 64 + ib * 16 + l4 * 4 + rr;
                pm1s[row * 2 + wc] = m1; pm2s[row * 2 + wc] = m2; pjs[row * 2 + wc] = j1;
            }
        }
    __syncthreads();
    int grow0 = b * T_ + it * 128;
    if (tid < 128){
        float M1 = -1e30f, M2 = -1e30f; int J1 = 0;
        #pragma unroll
        for (int c2 = 0; c2 < 2; ++c2){   // ascending col halves: ties keep lower j
            float a1 = pm1s[tid * 2 + c2], a2 = pm2s[tid * 2 + c2]; int aj = pjs[tid * 2 + c2];
            if (a1 > M1){ M2 = fmaxf(M1, a2); M1 = a1; J1 = aj; }
            else { M2 = fmaxf(M2, a1); }
        }
        long pidx = (long)(grow0 + tid) * 4 + jt;
        pmax1[pidx] = M1; pmax2[pidx] = M2; pj1[pidx] = jt * 128 + J1;
        m1blk[tid] = M1;
    }
    __syncthreads();
    // candidate emission vs BLOCK max (superset of global window)
    #pragma unroll
    for (int ib = 0; ib < 4; ++ib)
        #pragma unroll
        for (int rr = 0; rr < 4; ++rr){
            int row = wr * 64 + ib * 16 + l4 * 4 + rr;
            if (it == 0 && row == 0) continue;       // i=0 always unmerged
            float thr_ = m1blk[row] - TAU_C;
            #pragma unroll
            for (int jb = 0; jb < 4; ++jb){
                float v = acc[ib][jb][rr];
                if (v > thr_){
                    int idx = atomicAdd(pcnt_s, 1);
                    int2 pr = make_int2(grow0 + row, jt * 128 + wc * 64 + jb * 16 + l15);
                    if (idx < PBUF_){ pb_ij[idx] = pr; pb_v[idx] = v; }
                    else { int p = atomicAdd(paircnt, 1); pairs_ij[p] = pr; pairv[p] = v; }
                }
            }
        }
    __syncthreads();
    if (tid == 0) *pbase_s = atomicAdd(paircnt, min(*pcnt_s, PBUF_));
    __syncthreads();
    int n = min(*pcnt_s, PBUF_);
    for (int k2 = tid; k2 < n; k2 += 256){
        pairs_ij[*pbase_s + k2] = pb_ij[k2];
        pairv  [*pbase_s + k2] = pb_v[k2];
    }
}

// ---------------- reduce: merge 4 col-blocks -> node_idx, flag threshold, zero rowkey ----------------
__global__ __launch_bounds__(256) void reduce_k(const float* __restrict__ pmax1,
                                                const float* __restrict__ pmax2,
                                                const int*   __restrict__ pj1,
                                                int* __restrict__ node_idx,
                                                float* __restrict__ thr,
                                                unsigned long long* __restrict__ rowkey){
    int t = blockIdx.x * 256 + threadIdx.x;
    if (t >= B_ * T_) return;
    float M1 = -1e30f, M2 = -1e30f; int J1 = 0;
    #pragma unroll
    for (int cb = 0; cb < 4; ++cb){   // ascending jt: lowest-j tie rule preserved
        float a1 = pmax1[(long)t * 4 + cb], a2 = pmax2[(long)t * 4 + cb];
        int aj = pj1[(long)t * 4 + cb];
        if (a1 > M1){ M2 = fmaxf(M1, a2); M1 = a1; J1 = aj; }
        else { M2 = fmaxf(M2, a1); }
    }
    node_idx[t] = J1;
    thr[t] = ((t & (T_ - 1)) != 0 && (M1 - M2) < TAU_C) ? (M1 - TAU_C) : 3.0e38f;
    rowkey[t] = 0ULL;
}

// ---------------- refine: filter pairs by global window, fp64 exact, atomicMax keyed winner ----------------
__global__ __launch_bounds__(256) void refine_k(const float* __restrict__ hs,
                                                const double* __restrict__ nsq,
                                                const int* __restrict__ paircnt,
                                                const int2* __restrict__ pairs_ij,
                                                const float* __restrict__ pairv,
                                                const float* __restrict__ thr,
                                                unsigned long long* __restrict__ rowkey){
    int n = *paircnt;
    int w = threadIdx.x >> 6, lane = threadIdx.x & 63;
    for (int p = blockIdx.x * 4 + w; p < n; p += gridDim.x * 4){
        int2 pr = pairs_ij[p];
        int grow = pr.x, j = pr.y;
        if (pairv[p] <= thr[grow]) continue;   // unflagged row or below global window
        int b = grow >> 9, i = grow & 511;
        const float* ar = hs + ((long)b * L_ + 2 * i) * D_;
        const float* br = hs + ((long)b * L_ + 2 * j + 1) * D_;
        double s = 0.0;
        #pragma unroll
        for (int dd = 0; dd < 12; ++dd){
            int d = dd * 64 + lane;
            s += (double)ar[d] * (double)br[d];
        }
        #pragma unroll
        for (int off = 32; off; off >>= 1) s += __shfl_xor(s, off);
        if (lane == 0){
            double sc = s / sqrt(nsq[(long)b * L_ + 2 * j + 1]);  // row-uniform 1/|a_i| dropped
            unsigned long long bits = (unsigned long long)__double_as_longlong(sc);
            unsigned long long key = (bits >> 63) ? ~bits : (bits | 0x8000000000000000ULL);
            key = (key & ~0xFFFFULL) | (unsigned long long)(511 - j);  // ties -> lowest j
            atomicMax(&rowkey[grow], key);
        }
    }
}

// ---------------- deterministic CSR (stable by source index), rowkey override ----------------
__global__ __launch_bounds__(512) void csr_k(const int* __restrict__ node_idx,
                                             const unsigned long long* __restrict__ rowkey,
                                             int* __restrict__ goff,
                                             int* __restrict__ glist){
    __shared__ int sidx[512];
    __shared__ int off[513];
    __shared__ int tmp[512];
    __shared__ int cnt[512];
    int b = blockIdx.x, t = threadIdx.x;
    unsigned long long rk = rowkey[b * T_ + t];
    sidx[t] = rk ? (511 - (int)(rk & 0xFFFFULL)) : node_idx[b * T_ + t];
    cnt[t] = 0;
    __syncthreads();
    if (t >= 1) atomicAdd(&cnt[sidx[t]], 1);   // i=0 excluded (always unmerged)
    __syncthreads();
    tmp[t] = cnt[t];
    __syncthreads();
    for (int s = 1; s < 512; s <<= 1){
        int v = (t >= s) ? tmp[t - s] : 0;
        __syncthreads();
        tmp[t] += v;
        __syncthreads();
    }
    if (t == 0) off[0] = 0;
    off[t + 1] = tmp[t];
    __syncthreads();
    if (t >= 1){
        int j = sidx[t], r = 0;
        for (int i2 = 1; i2 < t; ++i2) r += (sidx[i2] == j);  // stable rank
        glist[b * T_ + off[j] + r] = t;
    }
    goff[b * 513 + t] = off[t];
    if (t == 0) goff[b * 513 + 512] = off[512];
}

// ---------------- merge: float4 gather-mean per dst token (+mask) ----------------
__global__ __launch_bounds__(192) void merge_k(const float* __restrict__ hs,
                                               const int* __restrict__ goff,
                                               const int* __restrict__ glist,
                                               float* __restrict__ out){
    int bid = blockIdx.x;
    int b = bid / DT_, jj = bid - b * DT_;
    long obase4 = ((long)b * DT_ + jj) * (D_ / 4);
    float4* out4 = (float4*)out;
    if (threadIdx.x == 0) out[(long)B_ * DT_ * D_ + b * DT_ + jj] = 0.0f;  // mask
    int d = threadIdx.x;
    if (jj == 0){  // unmerged token = src[0] = seq 0
        const float4* src = (const float4*)(hs + (long)b * L_ * D_);
        out4[obase4 + d] = src[d];
        return;
    }
    int j = jj - 1;
    int o0 = goff[b * 513 + j], o1 = goff[b * 513 + j + 1];
    const float4* dst = (const float4*)(hs + ((long)b * L_ + 2 * j + 1) * D_);
    float4 a = dst[d];
    for (int s = o0; s < o1; ++s){   // ascending source index: deterministic
        int i = glist[b * T_ + s];
        const float4* srow = (const float4*)(hs + ((long)b * L_ + 2 * i) * D_);
        float4 v = srow[d];
        a.x += v.x; a.y += v.y; a.z += v.z; a.w += v.w;
    }
    float rc = 1.0f / (float)(o1 - o0 + 1);
    a.x *= rc; a.y *= rc; a.z *= rc; a.w *= rc;
    out4[obase4 + d] = a;
}

extern "C" void kernel_launch(void* const* d_in, const int* in_sizes, int n_in,
                              void* d_out, int out_size, void* d_ws, size_t ws_size,
                              hipStream_t stream){
    const float* hs = (const float*)d_in[0];  // (128,1024,768) f32
    float* out = (float*)d_out;
    char* ws = (char*)d_ws;

    const long PSZ = (long)B_ * CH_ * T_ * 8;          // 50,331,648 shorts = 100.66 MB
    unsigned short* Apk = (unsigned short*)ws;
    unsigned short* Bpk = Apk + PSZ;                   // ends at 201,326,592 B
    double* nsq      = (double*)(ws + 201326592);      // 1 MB (odd entries)
    int*    node_idx = (int*)   (ws + 202375168);      // 256 KB
    unsigned long long* rowkey = (unsigned long long*)(ws + 202637312); // 512 KB
    int*    paircnt  = (int*)   (ws + 203161600);      // 256 B
    int*    goff     = (int*)   (ws + 203161856);      // 263168 B
    int*    glist    = (int*)   (ws + 203425024);      // 262144 B
    float*  pmax1    = (float*) (ws + 203687168);      // 1 MB  (B*T*4)
    float*  pmax2    = (float*) (ws + 204735744);      // 1 MB
    int*    pj1      = (int*)   (ws + 205784320);      // 1 MB
    float*  thr      = (float*) (ws + 206832896);      // 256 KB
    int2*   pairs_ij = (int2*)  (ws + 207095040);      // 16 MB cap (2M pairs)
    float*  pairv    = (float*) (ws + 223872256);      // 8 MB

    pack_k  <<<B_ * 64, 256, 0, stream>>>(hs, Apk, Bpk, nsq, paircnt);
    coarse_k<<<2048, 256, 0, stream>>>(Apk, Bpk, pmax1, pmax2, pj1, paircnt, pairs_ij, pairv);
    reduce_k<<<B_ * T_ / 256, 256, 0, stream>>>(pmax1, pmax2, pj1, node_idx, thr, rowkey);
    refine_k<<<512, 256, 0, stream>>>(hs, nsq, paircnt, pairs_ij, pairv, thr, rowkey);
    csr_k   <<<B_, 512, 0, stream>>>(node_idx, rowkey, goff, glist);
    merge_k <<<B_ * DT_, 192, 0, stream>>>(hs, goff, glist, out);
}

// Round 14
// 328.737 us; speedup vs baseline: 1.2074x; 1.2074x over previous
//
#include <hip/hip_runtime.h>
#include <hip/hip_bf16.h>

#define B_ 128
#define L_ 1024
#define T_ 512   // L/2 tokens per parity
#define D_ 768
#define CH_ 96   // D/8 chunks of 8 elems
#define DT_ 513  // output tokens per batch
#define TAU_C 1e-3f   // coarse candidate window (~14 sigma of single-bf16 coarse error)
#define PBUF_ 1024

// coarse LDS ring: slot = one k-step (4 chunks) of B(512 toks) + A(128 toks)
#define KS_B_CSTR 8208                       // 512*16 + 16 pad
#define KS_B_BYTES (4 * KS_B_CSTR)           // 32832
#define KS_A_CSTR 2064                       // 128*16 + 16 pad
#define KS_A_BYTES (4 * KS_A_CSTR)           // 8256
#define KS_BYTES (KS_B_BYTES + KS_A_BYTES)   // 41088
#define SMEM_BYTES (3 * KS_BYTES)            // 123264 <= 160K

typedef __attribute__((ext_vector_type(8))) short bf16x8;
typedef __attribute__((ext_vector_type(4))) float f32x4;

typedef const __attribute__((address_space(1))) unsigned int* gas1_t;
typedef __attribute__((address_space(3))) unsigned int* gas3_t;

__device__ __forceinline__ unsigned short f2bf_rne(float x){
    unsigned u = __float_as_uint(x);
    unsigned r = (u + 0x7FFFu + ((u >> 16) & 1u)) >> 16;
    return (unsigned short)r;
}

// ---------------- pack: ALL tokens -> fp64 norm + single bf16, chunk-major per parity ----------------
__global__ __launch_bounds__(256) void pack_k(const float* __restrict__ hs,
                                              unsigned short* __restrict__ Apk,
                                              unsigned short* __restrict__ Bpk,
                                              double* __restrict__ nsq,
                                              int* __restrict__ paircnt){
    __shared__ __align__(16) unsigned short LhS[CH_ * 16 * 8];  // 24.6 KB
    if (blockIdx.x == 0 && threadIdx.x == 0) *paircnt = 0;
    int b = blockIdx.x >> 6, g = blockIdx.x & 63;   // 16 seq tokens per block
    int wv = threadIdx.x >> 6, lane = threadIdx.x & 63;

    #pragma unroll
    for (int rr = 0; rr < 4; ++rr){
        int jj = wv * 4 + rr;                       // 0..15 within block
        long seq = (long)b * L_ + g * 16 + jj;
        const float4* src = (const float4*)(hs + seq * D_);
        float4 f0 = src[lane], f1 = src[lane + 64], f2 = src[lane + 128];
        double s = 0.0;
        s += (double)f0.x*f0.x + (double)f0.y*f0.y + (double)f0.z*f0.z + (double)f0.w*f0.w;
        s += (double)f1.x*f1.x + (double)f1.y*f1.y + (double)f1.z*f1.z + (double)f1.w*f1.w;
        s += (double)f2.x*f2.x + (double)f2.y*f2.y + (double)f2.z*f2.z + (double)f2.w*f2.w;
        #pragma unroll
        for (int off = 32; off; off >>= 1) s += __shfl_xor(s, off);
        if (lane == 0 && (jj & 1)) nsq[seq] = s;    // odd-token norms for refine
        float rn = (float)(1.0 / sqrt(s));
        float4 fv[3] = {f0, f1, f2};
        #pragma unroll
        for (int t = 0; t < 3; ++t){
            int e0 = t * 256 + lane * 4;
            int c = e0 >> 3, ei = e0 & 7;           // ei = 0 or 4
            float vv[4] = {fv[t].x, fv[t].y, fv[t].z, fv[t].w};
            short4 hv;
            #pragma unroll
            for (int e = 0; e < 4; ++e)
                ((short*)&hv)[e] = (short)f2bf_rne(vv[e] * rn);
            int o = c * 128 + ((jj ^ (c & 7)) << 3) + ei;   // XOR-swizzled (shorts)
            *(short4*)(LhS + o) = hv;
        }
    }
    __syncthreads();
    #pragma unroll
    for (int it = 0; it < 6; ++it){
        int linear = it * 256 + threadIdx.x;
        int c = linear >> 4, jj = linear & 15;
        int o = c * 128 + ((jj ^ (c & 7)) << 3);
        int tok = g * 8 + (jj >> 1);
        long go = ((long)(b * CH_ + c) * T_ + tok) * 8;
        if (jj & 1) *(bf16x8*)(Bpk + go) = *(const bf16x8*)(LhS + o);
        else        *(bf16x8*)(Apk + go) = *(const bf16x8*)(LhS + o);
    }
}

// ---------------- coarse: 128x512 tile, A+B streamed in 3-slot k-step ring (stage-2-ahead),
//                  counted vmcnt(5), 1 barrier/k-step, 32 MFMA/wave/step ----------------
// 8 waves as 2x4: wave (wr,wc) owns rows wr*64..+63, cols wc*128..+127.
__global__ __launch_bounds__(512, 2) void coarse_k(const unsigned short* __restrict__ Apk,
                                                   const unsigned short* __restrict__ Bpk,
                                                   int* __restrict__ node_idx,
                                                   unsigned long long* __restrict__ rowkey,
                                                   int* __restrict__ paircnt,
                                                   int2* __restrict__ pairs){
    __shared__ __align__(16) char SMEM[SMEM_BYTES];

    int bid = blockIdx.x;                 // 512 blocks
    int xcd = bid & 7, q = bid >> 3;
    int it = q & 3, bhi = q >> 2;
    int b = xcd + 8 * bhi;                // same-b blocks co-scheduled on one XCD

    int tid = threadIdx.x;
    int w = tid >> 6, lane = tid & 63, l15 = lane & 15, l4 = lane >> 4;
    int wr = w >> 2, wc = w & 3;

    long pkbase = (long)b * CH_ * T_;     // units of 8 shorts

    // stage k-step s_ into ring slot: per wave 4 B instrs (one chunk-row each) + 1 A instr
    #define STAGE(s_, slot_) do {                                                          \
        char* dst_ = SMEM + (slot_) * KS_BYTES;                                            \
        _Pragma("unroll")                                                                  \
        for (int n_ = 0; n_ < 4; ++n_){                                                    \
            const unsigned short* sp_ = Bpk + (pkbase + (long)((s_)*4 + n_) * T_ + w * 64 + lane) * 8; \
            __builtin_amdgcn_global_load_lds((gas1_t)sp_, (gas3_t)(dst_ + n_ * KS_B_CSTR + w * 1024), 16, 0, 0); \
        }                                                                                  \
        {                                                                                  \
            const unsigned short* sp_ = Apk + (pkbase + (long)((s_)*4 + (w >> 1)) * T_ + it * 128 + (w & 1) * 64 + lane) * 8; \
            __builtin_amdgcn_global_load_lds((gas1_t)sp_, (gas3_t)(dst_ + KS_B_BYTES + (w >> 1) * KS_A_CSTR + (w & 1) * 1024), 16, 0, 0); \
        }                                                                                  \
    } while (0)

    // prologue: stage k-steps 0,1
    STAGE(0, 0); STAGE(1, 1);

    f32x4 acc[4][8];   // row = wr*64 + ib*16 + l4*4+rr, col = wc*128 + jb*16 + l15
    #pragma unroll
    for (int i = 0; i < 4; ++i)
        #pragma unroll
        for (int j = 0; j < 8; ++j) acc[i][j] = (f32x4){0.f, 0.f, 0.f, 0.f};

    __syncthreads();   // drains prologue stages

    #pragma unroll 3
    for (int s = 0; s < 24; ++s){
        if (s < 22) STAGE(s + 2, (s + 2) % 3);
        const char* slot = SMEM + (s % 3) * KS_BYTES;
        bf16x8 ah[4], bh[8];
        #pragma unroll
        for (int ib = 0; ib < 4; ++ib)
            ah[ib] = *(const bf16x8*)(slot + KS_B_BYTES + l4 * KS_A_CSTR + (wr * 64 + ib * 16 + l15) * 16);
        #pragma unroll
        for (int jb = 0; jb < 8; ++jb)
            bh[jb] = *(const bf16x8*)(slot + l4 * KS_B_CSTR + (wc * 128 + jb * 16 + l15) * 16);
        __builtin_amdgcn_s_setprio(1);
        #pragma unroll
        for (int jb = 0; jb < 8; ++jb)
            #pragma unroll
            for (int ib = 0; ib < 4; ++ib)
                acc[ib][jb] = __builtin_amdgcn_mfma_f32_16x16x32_bf16(ah[ib], bh[jb], acc[ib][jb], 0, 0, 0);
        __builtin_amdgcn_s_setprio(0);
        if (s < 22)      asm volatile("s_waitcnt vmcnt(5)" ::: "memory");
        else             asm volatile("s_waitcnt vmcnt(0)" ::: "memory");
        __builtin_amdgcn_s_barrier();
        asm volatile("" ::: "memory");
    }
    #undef STAGE

    // ---- epilogue (SMEM overlay; ring free after final barrier) ----
    float* pm1s = (float*)SMEM;               // [128][4]
    int*   pjs  = (int*)(SMEM + 2048);        // [128][4]
    float* m1f  = (float*)(SMEM + 4096);      // [128]
    int*   cnd  = (int*)(SMEM + 4608);        // [128]
    int2*  pbuf = (int2*)(SMEM + 5120);       // [1024]
    int*   pcnt_s  = (int*)(SMEM + 13312);
    int*   pbase_s = (int*)(SMEM + 13316);

    #pragma unroll
    for (int ib = 0; ib < 4; ++ib)
        #pragma unroll
        for (int rr = 0; rr < 4; ++rr){
            float m1 = -1e30f; int j1 = 0;
            #pragma unroll
            for (int jb = 0; jb < 8; ++jb){   // ascending cols: strict > keeps lowest j
                float v = acc[ib][jb][rr];
                int col = wc * 128 + jb * 16 + l15;
                if (v > m1){ m1 = v; j1 = col; }
            }
            #pragma unroll
            for (int m = 1; m < 16; m <<= 1){
                float o1 = __shfl_xor(m1, m);
                int   oj = __shfl_xor(j1, m);
                if (o1 > m1 || (o1 == m1 && oj < j1)){ m1 = o1; j1 = oj; }
            }
            if (l15 == 0){
                int row = wr * 64 + ib * 16 + l4 * 4 + rr;
                pm1s[row * 4 + wc] = m1; pjs[row * 4 + wc] = j1;
            }
        }
    __syncthreads();
    int grow0 = b * T_ + it * 128;
    if (tid < 128){
        float M1 = -1e30f; int J1 = 0;
        #pragma unroll
        for (int c2 = 0; c2 < 4; ++c2){   // ascending col blocks: ties keep lower j
            float a1 = pm1s[tid * 4 + c2]; int aj = pjs[tid * 4 + c2];
            if (a1 > M1 || (a1 == M1 && aj < J1)){ M1 = a1; J1 = aj; }
        }
        node_idx[grow0 + tid] = J1;
        m1f[tid] = M1;
        cnd[tid] = 0;
        rowkey[grow0 + tid] = 0ULL;
        if (tid == 0) *pcnt_s = 0;
    }
    __syncthreads();
    // candidate count per row (16-lane shfl reduce -> 1 atomic per group)
    #pragma unroll
    for (int ib = 0; ib < 4; ++ib)
        #pragma unroll
        for (int rr = 0; rr < 4; ++rr){
            int row = wr * 64 + ib * 16 + l4 * 4 + rr;
            float thr_ = m1f[row] - TAU_C;
            int hits = 0;
            #pragma unroll
            for (int jb = 0; jb < 8; ++jb) hits += (acc[ib][jb][rr] > thr_) ? 1 : 0;
            #pragma unroll
            for (int m = 1; m < 16; m <<= 1) hits += __shfl_xor(hits, m);
            if (l15 == 0 && hits) atomicAdd(&cnd[row], hits);
        }
    __syncthreads();
    #pragma unroll
    for (int ib = 0; ib < 4; ++ib)
        #pragma unroll
        for (int rr = 0; rr < 4; ++rr){
            int row = wr * 64 + ib * 16 + l4 * 4 + rr;
            if (cnd[row] < 2) continue;
            if (it == 0 && row == 0) continue;       // i=0 always unmerged
            float thr_ = m1f[row] - TAU_C;
            #pragma unroll
            for (int jb = 0; jb < 8; ++jb)
                if (acc[ib][jb][rr] > thr_){
                    int idx = atomicAdd(pcnt_s, 1);
                    int2 pr = make_int2(grow0 + row, wc * 128 + jb * 16 + l15);
                    if (idx < PBUF_) pbuf[idx] = pr;
                    else { int p = atomicAdd(paircnt, 1); pairs[p] = pr; }
                }
        }
    __syncthreads();
    if (tid == 0) *pbase_s = atomicAdd(paircnt, min(*pcnt_s, PBUF_));
    __syncthreads();
    int n = min(*pcnt_s, PBUF_);
    for (int k2 = tid; k2 < n; k2 += 512) pairs[*pbase_s + k2] = pbuf[k2];
}

// ---------------- refine: fp64 exact score for candidate pairs, atomicMax keyed winner ----------------
__global__ __launch_bounds__(256) void refine_k(const float* __restrict__ hs,
                                                const double* __restrict__ nsq,
                                                const int* __restrict__ paircnt,
                                                const int2* __restrict__ pairs,
                                                unsigned long long* __restrict__ rowkey){
    int n = *paircnt;
    int w = threadIdx.x >> 6, lane = threadIdx.x & 63;
    for (int p = blockIdx.x * 4 + w; p < n; p += gridDim.x * 4){
        int2 pr = pairs[p];
        int grow = pr.x, j = pr.y;
        int b = grow >> 9, i = grow & 511;
        const float* ar = hs + ((long)b * L_ + 2 * i) * D_;
        const float* br = hs + ((long)b * L_ + 2 * j + 1) * D_;
        double s = 0.0;
        #pragma unroll
        for (int dd = 0; dd < 12; ++dd){
            int d = dd * 64 + lane;
            s += (double)ar[d] * (double)br[d];
        }
        #pragma unroll
        for (int off = 32; off; off >>= 1) s += __shfl_xor(s, off);
        if (lane == 0){
            double sc = s / sqrt(nsq[(long)b * L_ + 2 * j + 1]);  // row-uniform 1/|a_i| dropped
            unsigned long long bits = (unsigned long long)__double_as_longlong(sc);
            unsigned long long key = (bits >> 63) ? ~bits : (bits | 0x8000000000000000ULL);
            key = (key & ~0xFFFFULL) | (unsigned long long)(511 - j);  // ties -> lowest j
            atomicMax(&rowkey[grow], key);
        }
    }
}

// ---------------- deterministic CSR (stable by source index), rowkey override ----------------
__global__ __launch_bounds__(512) void csr_k(const int* __restrict__ node_idx,
                                             const unsigned long long* __restrict__ rowkey,
                                             int* __restrict__ goff,
                                             int* __restrict__ glist){
    __shared__ int sidx[512];
    __shared__ int off[513];
    __shared__ int tmp[512];
    __shared__ int cnt[512];
    int b = blockIdx.x, t = threadIdx.x;
    unsigned long long rk = rowkey[b * T_ + t];
    sidx[t] = rk ? (511 - (int)(rk & 0xFFFFULL)) : node_idx[b * T_ + t];
    cnt[t] = 0;
    __syncthreads();
    if (t >= 1) atomicAdd(&cnt[sidx[t]], 1);   // i=0 excluded (always unmerged)
    __syncthreads();
    tmp[t] = cnt[t];
    __syncthreads();
    for (int s = 1; s < 512; s <<= 1){
        int v = (t >= s) ? tmp[t - s] : 0;
        __syncthreads();
        tmp[t] += v;
        __syncthreads();
    }
    if (t == 0) off[0] = 0;
    off[t + 1] = tmp[t];
    __syncthreads();
    if (t >= 1){
        int j = sidx[t], r = 0;
        for (int i2 = 1; i2 < t; ++i2) r += (sidx[i2] == j);  // stable rank
        glist[b * T_ + off[j] + r] = t;
    }
    goff[b * 513 + t] = off[t];
    if (t == 0) goff[b * 513 + 512] = off[512];
}

// ---------------- merge: float4 gather-mean per dst token (+mask) ----------------
__global__ __launch_bounds__(192) void merge_k(const float* __restrict__ hs,
                                               const int* __restrict__ goff,
                                               const int* __restrict__ glist,
                                               float* __restrict__ out){
    int bid = blockIdx.x;
    int b = bid / DT_, jj = bid - b * DT_;
    long obase4 = ((long)b * DT_ + jj) * (D_ / 4);
    float4* out4 = (float4*)out;
    if (threadIdx.x == 0) out[(long)B_ * DT_ * D_ + b * DT_ + jj] = 0.0f;  // mask
    int d = threadIdx.x;
    if (jj == 0){  // unmerged token = src[0] = seq 0
        const float4* src = (const float4*)(hs + (long)b * L_ * D_);
        out4[obase4 + d] = src[d];
        return;
    }
    int j = jj - 1;
    int o0 = goff[b * 513 + j], o1 = goff[b * 513 + j + 1];
    const float4* dst = (const float4*)(hs + ((long)b * L_ + 2 * j + 1) * D_);
    float4 a = dst[d];
    for (int s = o0; s < o1; ++s){   // ascending source index: deterministic
        int i = glist[b * T_ + s];
        const float4* srow = (const float4*)(hs + ((long)b * L_ + 2 * i) * D_);
        float4 v = srow[d];
        a.x += v.x; a.y += v.y; a.z += v.z; a.w += v.w;
    }
    float rc = 1.0f / (float)(o1 - o0 + 1);
    a.x *= rc; a.y *= rc; a.z *= rc; a.w *= rc;
    out4[obase4 + d] = a;
}

extern "C" void kernel_launch(void* const* d_in, const int* in_sizes, int n_in,
                              void* d_out, int out_size, void* d_ws, size_t ws_size,
                              hipStream_t stream){
    const float* hs = (const float*)d_in[0];  // (128,1024,768) f32
    float* out = (float*)d_out;
    char* ws = (char*)d_ws;

    const long PSZ = (long)B_ * CH_ * T_ * 8;          // 50,331,648 shorts = 100.66 MB
    unsigned short* Apk = (unsigned short*)ws;
    unsigned short* Bpk = Apk + PSZ;                   // ends at 201,326,592 B
    double* nsq      = (double*)(ws + 201326592);      // 1 MB (odd entries)
    int*    node_idx = (int*)   (ws + 202375168);      // 256 KB
    unsigned long long* rowkey = (unsigned long long*)(ws + 202637312); // 512 KB
    int*    paircnt  = (int*)   (ws + 203161600);      // 256 B
    int*    goff     = (int*)   (ws + 203161856);      // 263168 B
    int*    glist    = (int*)   (ws + 203425024);      // 262144 B
    int2*   pairs    = (int2*)  (ws + 203687168);      // large cap, fits ws

    pack_k  <<<B_ * 64, 256, 0, stream>>>(hs, Apk, Bpk, nsq, paircnt);
    coarse_k<<<512, 512, 0, stream>>>(Apk, Bpk, node_idx, rowkey, paircnt, pairs);
    refine_k<<<512, 256, 0, stream>>>(hs, nsq, paircnt, pairs, rowkey);
    csr_k   <<<B_, 512, 0, stream>>>(node_idx, rowkey, goff, glist);
    merge_k <<<B_ * DT_, 192, 0, stream>>>(hs, goff, glist, out);
}